// Round 1
// baseline (530.657 us; speedup 1.0000x reference)
//
#include <hip/hip_runtime.h>
#include <math.h>

static constexpr int NN = 40000;   // nodes
static constexpr int NE = 640000;  // edges
static constexpr int DD = 128;     // feature dim
// H=4, DK=DE=32, P=1, n_layer=0

// ---------- float <-> ordered-uint encoding for atomic max ----------
__device__ __forceinline__ unsigned enc_f(float f) {
  unsigned u = __float_as_uint(f);
  return (u & 0x80000000u) ? ~u : (u | 0x80000000u);
}
__device__ __forceinline__ float dec_f(unsigned e) {
  unsigned u = (e & 0x80000000u) ? (e & 0x7FFFFFFFu) : ~e;
  return __uint_as_float(u);
}

// ---------------------------------------------------------------
// Fused LayerNorm + QKV projection GEMM.
// grid: (NN/64, 9) ; blockIdx.y = mat*3 + t ; block = 256 threads
// Output layout: O[t][node][h*32+k]  (3 * NN * 128 floats per matrix)
// ---------------------------------------------------------------
__global__ __launch_bounds__(256)
void qkv_kernel(const float* __restrict__ x,
                const float* __restrict__ gamma, const float* __restrict__ beta,
                const float* __restrict__ Wq, const float* __restrict__ bq,
                const float* __restrict__ Wk, const float* __restrict__ bk,
                const float* __restrict__ Wv, const float* __restrict__ bv,
                float* __restrict__ Qo, float* __restrict__ Ko, float* __restrict__ Vo)
{
  __shared__ float xs[64][129];   // LN'd x tile, padded
  __shared__ float wsh[32][128];  // weight K-slab
  const int tid = threadIdx.x;
  const int n0 = blockIdx.x * 64;
  const int combo = blockIdx.y;
  const int mat = combo / 3, t = combo % 3;
  const float* W; const float* B; float* O;
  if (mat == 0)      { W = Wq; B = bq; O = Qo; }
  else if (mat == 1) { W = Wk; B = bk; O = Ko; }
  else               { W = Wv; B = bv; O = Vo; }

  // ---- load x tile (64 x 128) ----
#pragma unroll
  for (int i = 0; i < 8; ++i) {
    int f4 = tid + i * 256;          // 0..2047 float4s
    int r  = f4 >> 5;
    int c4 = (f4 & 31) * 4;
    float4 v = *reinterpret_cast<const float4*>(x + (size_t)(n0 + r) * DD + c4);
    xs[r][c4 + 0] = v.x; xs[r][c4 + 1] = v.y; xs[r][c4 + 2] = v.z; xs[r][c4 + 3] = v.w;
  }
  __syncthreads();

  // ---- LayerNorm, 4 threads per row ----
  {
    int r = tid >> 2, l = tid & 3;
    float s = 0.f, ss = 0.f;
#pragma unroll
    for (int c = l; c < DD; c += 4) { float v = xs[r][c]; s += v; ss += v * v; }
    s  += __shfl_xor(s, 1);  ss += __shfl_xor(ss, 1);
    s  += __shfl_xor(s, 2);  ss += __shfl_xor(ss, 2);
    float mu  = s * (1.f / 128.f);
    float var = ss * (1.f / 128.f) - mu * mu;
    float rs  = rsqrtf(var + 1e-5f);
#pragma unroll
    for (int c = l; c < DD; c += 4)
      xs[r][c] = (xs[r][c] - mu) * rs * gamma[c] + beta[c];
  }
  __syncthreads();

  // ---- GEMM: 64 rows x 128 cols, micro-tile 4x8 per thread ----
  const int tx = tid & 15, ty = tid >> 4;
  float acc[4][8];
#pragma unroll
  for (int j = 0; j < 8; ++j) {
    int c = tx * 8 + j;
    float bb = B[((c >> 5) * 3 + t) * 32 + (c & 31)];  // bias (H,P=1,3,32)
#pragma unroll
    for (int i = 0; i < 4; ++i) acc[i][j] = bb;
  }

  for (int ks = 0; ks < 4; ++ks) {
    // stage W[ks*32 .. +32][all 128 cols]; W layout (H,1,3,D,32)
#pragma unroll
    for (int i = 0; i < 16; ++i) {
      int idx = tid + i * 256;        // 0..4095
      int dd = idx >> 7, c = idx & 127;
      wsh[dd][c] = W[(size_t)(((c >> 5) * 3 + t) * 128 + ks * 32 + dd) * 32 + (c & 31)];
    }
    __syncthreads();
#pragma unroll 8
    for (int dd = 0; dd < 32; ++dd) {
      float aa[4];
#pragma unroll
      for (int i = 0; i < 4; ++i) aa[i] = xs[ty * 4 + i][ks * 32 + dd];
      float4 b0 = *reinterpret_cast<float4*>(&wsh[dd][tx * 8]);
      float4 b1 = *reinterpret_cast<float4*>(&wsh[dd][tx * 8 + 4]);
      float bb[8] = {b0.x, b0.y, b0.z, b0.w, b1.x, b1.y, b1.z, b1.w};
#pragma unroll
      for (int i = 0; i < 4; ++i)
#pragma unroll
        for (int j = 0; j < 8; ++j)
          acc[i][j] += aa[i] * bb[j];
    }
    __syncthreads();
  }

  // ---- store ----
#pragma unroll
  for (int i = 0; i < 4; ++i) {
    int r = n0 + ty * 4 + i;
    float4 o0 = make_float4(acc[i][0], acc[i][1], acc[i][2], acc[i][3]);
    float4 o1 = make_float4(acc[i][4], acc[i][5], acc[i][6], acc[i][7]);
    float* p = O + ((size_t)t * NN + r) * DD + tx * 8;
    *reinterpret_cast<float4*>(p)     = o0;
    *reinterpret_cast<float4*>(p + 4) = o1;
  }
}

// ---------------------------------------------------------------
// Edge histogram by dst
// ---------------------------------------------------------------
__global__ __launch_bounds__(256)
void hist_kernel(const int* __restrict__ ei, int* __restrict__ deg)
{
  int e = blockIdx.x * 256 + threadIdx.x;
  if (e < NE) atomicAdd(&deg[ei[NE + e]], 1);
}

// ---------------------------------------------------------------
// Single-block exclusive prefix scan of deg[NN] -> base[NN+1]
// ---------------------------------------------------------------
__global__ __launch_bounds__(1024)
void scan_kernel(const int* __restrict__ deg, int* __restrict__ base)
{
  __shared__ int sdata[1024];
  __shared__ int carry;
  const int tid = threadIdx.x;
  if (tid == 0) carry = 0;
  __syncthreads();
  for (int start = 0; start < NN; start += 1024) {
    int i = start + tid;
    int v = (i < NN) ? deg[i] : 0;
    sdata[tid] = v;
    __syncthreads();
    for (int off = 1; off < 1024; off <<= 1) {
      int tv = 0;
      if (tid >= off) tv = sdata[tid - off];
      __syncthreads();
      sdata[tid] += tv;
      __syncthreads();
    }
    int incl = sdata[tid];
    if (i < NN) base[i] = carry + incl - v;   // exclusive
    __syncthreads();
    if (tid == 0) carry += sdata[1023];
    __syncthreads();
  }
  if (tid == 0) base[NN] = carry;  // == NE
}

// ---------------------------------------------------------------
// Edge attention scores + CSR scatter + per-block head max.
// 4 threads per edge (one per head). grid = NE*4/256 = 10000 blocks.
// ---------------------------------------------------------------
__global__ __launch_bounds__(256)
void edge_att_kernel(const int* __restrict__ ei, const float* __restrict__ ev,
                     const float* __restrict__ m1, const float* __restrict__ m2,
                     const float* __restrict__ Q, const float* __restrict__ K,
                     const int* __restrict__ base, int* __restrict__ fill,
                     float* __restrict__ attp, int* __restrict__ code,
                     unsigned* __restrict__ blockmax)
{
  __shared__ unsigned smax[4];
  const int tid = threadIdx.x;
  if (tid < 4) smax[tid] = 0u;   // encoded -inf sentinel
  __syncthreads();

  const int g = blockIdx.x * 256 + tid;
  const int e = g >> 2;
  const int h = g & 3;
  const int src = ei[e];
  const int dst = ei[NE + e];
  const int t = (m1[e] > 0.5f) ? 1 : ((m2[e] > 0.5f) ? 2 : 0);

  const float* qr = Q + ((size_t)t * NN + dst) * DD + h * 32;
  const float* kr = K + ((size_t)t * NN + src) * DD + h * 32;
  float dot = 0.f;
#pragma unroll
  for (int i = 0; i < 8; ++i) {
    float4 a = reinterpret_cast<const float4*>(qr)[i];
    float4 b = reinterpret_cast<const float4*>(kr)[i];
    dot += a.x * b.x + a.y * b.y + a.z * b.z + a.w * b.w;
  }
  float av = fabsf(ev[e]);
  float decay = exp2f(-0.15200309344504995f * av);      // 0.9^|v|
  float ap = dot * 0.17677669529663687f * decay;        // /sqrt(32), *decay

  // slot via per-dst fill counter (one atomic per edge, lane h==0)
  int slot = 0;
  if (h == 0) slot = base[dst] + atomicAdd(&fill[dst], 1);
  slot = __shfl(slot, (tid & 63) & ~3);
  attp[(size_t)slot * 4 + h] = ap;
  if (h == 0) code[slot] = src | (t << 16);  // src < 65536

  // per-block max per head (lanes grouped by h = lane&3)
  float m = ap;
  m = fmaxf(m, __shfl_xor(m, 4));
  m = fmaxf(m, __shfl_xor(m, 8));
  m = fmaxf(m, __shfl_xor(m, 16));
  m = fmaxf(m, __shfl_xor(m, 32));
  if ((tid & 63) < 4) atomicMax(&smax[h], enc_f(m));
  __syncthreads();
  if (tid < 4) blockmax[blockIdx.x * 4 + tid] = smax[tid];
}

// ---------------------------------------------------------------
// Reduce per-block maxes -> gmax[4] floats. 1 block, 256 threads.
// ---------------------------------------------------------------
__global__ __launch_bounds__(256)
void max_reduce_kernel(const unsigned* __restrict__ blockmax, float* __restrict__ gmax, int nb)
{
  __shared__ unsigned sm[4];
  const int tid = threadIdx.x;
  const int h = tid & 3;
  if (tid < 4) sm[tid] = 0u;
  __syncthreads();
  unsigned m = 0u;
  for (int i = tid; i < nb * 4; i += 256) m = max(m, blockmax[i]);
  atomicMax(&sm[h], m);
  __syncthreads();
  if (tid < 4) gmax[tid] = dec_f(sm[tid]);
}

// ---------------------------------------------------------------
// Per-node aggregation: softmax denom + weighted V sum + residual + GeLU.
// One block (128 threads) per node.
// ---------------------------------------------------------------
__global__ __launch_bounds__(128)
void node_kernel(const float* __restrict__ x, const float* __restrict__ V,
                 const float* __restrict__ attp, const int* __restrict__ code,
                 const int* __restrict__ base, const float* __restrict__ gmax,
                 float* __restrict__ out)
{
  const int n = blockIdx.x;
  const int c = threadIdx.x;       // 0..127 ; component = h*32+k
  const int h = c >> 5;
  const float mx = gmax[h];
  const int b0 = base[n], b1 = base[n + 1];
  float acc = 0.f, den = 0.f;
  for (int j = b0; j < b1; ++j) {
    int cd = code[j];
    int s = cd & 0xFFFF;
    int t = cd >> 16;
    float a = __expf(attp[(size_t)j * 4 + h] - mx);
    den += a;
    acc += a * V[((size_t)t * NN + s) * DD + c];
  }
  float z = acc / (den + 1e-16f);
  float g = 0.5f * z * (1.0f + erff(z * 0.70710678118654752f));
  out[(size_t)n * DD + c] = x[(size_t)n * DD + c] + g;   // RES = 1.0
}

// ---------------------------------------------------------------
extern "C" void kernel_launch(void* const* d_in, const int* in_sizes, int n_in,
                              void* d_out, int out_size, void* d_ws, size_t ws_size,
                              hipStream_t stream)
{
  const float* x     = (const float*)d_in[0];
  const int*   ei    = (const int*)d_in[1];
  const float* ev    = (const float*)d_in[2];
  // d_in[3] time_nodes: unused by reference
  const float* m1    = (const float*)d_in[5];  // diff_time_same_var -> t=1
  const float* m2    = (const float*)d_in[6];  // diff_time_diff_var -> t=2
  // d_in[7] n_layer == 0 (P==1)
  const float* gamma = (const float*)d_in[8];
  const float* beta  = (const float*)d_in[9];
  const float* Wq    = (const float*)d_in[10];
  const float* bq    = (const float*)d_in[11];
  const float* Wk    = (const float*)d_in[12];
  const float* bk    = (const float*)d_in[13];
  const float* Wv    = (const float*)d_in[14];
  const float* bv    = (const float*)d_in[15];
  float* out = (float*)d_out;

  // ---- workspace layout (floats) ----
  float* ws = (float*)d_ws;
  float* Q    = ws;                       // 3*NN*128 = 15,360,000
  float* K    = Q + (size_t)3 * NN * DD;
  float* V    = K + (size_t)3 * NN * DD;
  float* attp = V + (size_t)3 * NN * DD;  // NE*4
  int*   code = (int*)(attp + (size_t)NE * 4);  // NE
  int*   deg  = code + NE;                // NN
  int*   fill = deg + NN;                 // NN
  int*   base = fill + NN;                // NN+1
  unsigned* blockmax = (unsigned*)(base + NN + 1);  // 40000
  float* gmax = (float*)(blockmax + 40000);         // 4

  // zero deg + fill (adjacent)
  hipMemsetAsync(deg, 0, (size_t)2 * NN * sizeof(int), stream);

  qkv_kernel<<<dim3(NN / 64, 9), 256, 0, stream>>>(x, gamma, beta, Wq, bq, Wk, bk, Wv, bv, Q, K, V);
  hist_kernel<<<NE / 256, 256, 0, stream>>>(ei, deg);
  scan_kernel<<<1, 1024, 0, stream>>>(deg, base);
  edge_att_kernel<<<(NE * 4) / 256, 256, 0, stream>>>(ei, ev, m1, m2, Q, K, base, fill, attp, code, blockmax);
  max_reduce_kernel<<<1, 256, 0, stream>>>(blockmax, gmax, (NE * 4) / 256);
  node_kernel<<<NN, 128, 0, stream>>>(x, V, attp, code, base, gmax, out);
}

// Round 3
// 301.795 us; speedup vs baseline: 1.7583x; 1.7583x over previous
//
#include <hip/hip_runtime.h>
#include <math.h>

static constexpr int NN = 40000;   // nodes
static constexpr int NE = 640000;  // edges
static constexpr int DD = 128;     // feature dim
// H=4, DK=DE=32, P=1, n_layer=0

typedef __attribute__((ext_vector_type(8))) short short8;
typedef __attribute__((ext_vector_type(4))) float f32x4;

// ---------- helpers ----------
__device__ __forceinline__ unsigned short f2b(float f) {
  unsigned u = __float_as_uint(f);
  unsigned r = (u + 0x7FFFu + ((u >> 16) & 1u)) >> 16;  // RNE
  return (unsigned short)r;
}
__device__ __forceinline__ float b2f(unsigned short b) {
  return __uint_as_float(((unsigned)b) << 16);
}
__device__ __forceinline__ unsigned enc_f(float f) {
  unsigned u = __float_as_uint(f);
  return (u & 0x80000000u) ? ~u : (u | 0x80000000u);
}
__device__ __forceinline__ float dec_f(unsigned e) {
  unsigned u = (e & 0x80000000u) ? (e & 0x7FFFFFFFu) : ~e;
  return __uint_as_float(u);
}
// T2-style XOR swizzle for 256B-pitch LDS rows (row = byte>>8)
__device__ __forceinline__ int swz(int b) {
  return b ^ ((((b >> 8) & 7) << 4));
}
__device__ __forceinline__ float pdot(unsigned a, unsigned b) {
  float al = __uint_as_float(a << 16), ah = __uint_as_float(a & 0xFFFF0000u);
  float bl = __uint_as_float(b << 16), bh = __uint_as_float(b & 0xFFFF0000u);
  return al * bl + ah * bh;
}

// ---------------------------------------------------------------
// One-time weight transpose: W[mat] (H,1,3,D,32) fp32 -> Wt[(mat*3+t)][c][d] bf16
// 9 blocks, one per (mat,t) slab.
// ---------------------------------------------------------------
__global__ __launch_bounds__(256)
void wt_kernel(const float* __restrict__ Wq, const float* __restrict__ Wk,
               const float* __restrict__ Wv, unsigned short* __restrict__ Wt)
{
  __shared__ unsigned short tile[128 * 136];
  const int slab = blockIdx.x;
  const int mat = slab / 3, t = slab % 3;
  const float* W = (mat == 0) ? Wq : (mat == 1) ? Wk : Wv;
#pragma unroll
  for (int i = 0; i < 64; ++i) {
    int idx = i * 256 + threadIdx.x;       // over h(4) x d(128) x k(32)
    int h = idx >> 12, d = (idx >> 5) & 127, k = idx & 31;
    float v = W[(size_t)(((h * 3 + t) * 128 + d)) * 32 + k];
    tile[d * 136 + h * 32 + k] = f2b(v);   // tile[d][c]
  }
  __syncthreads();
#pragma unroll
  for (int i = 0; i < 8; ++i) {
    int idx = i * 256 + threadIdx.x;       // 2048 chunks of 8
    int c = idx >> 4, ch = idx & 15;
    union { unsigned short s[8]; uint4 v; } u;
#pragma unroll
    for (int j = 0; j < 8; ++j) u.s[j] = tile[(ch * 8 + j) * 136 + c];
    *(uint4*)&Wt[(size_t)slab * 16384 + c * 128 + ch * 8] = u.v;
  }
}

// ---------------------------------------------------------------
// Fused LayerNorm + QKV projection, bf16 MFMA.
// grid (313, 9), block 256 (4 waves). 128-row x 128-col tile per block.
// Output O[t][node][c] bf16.
// ---------------------------------------------------------------
__global__ __launch_bounds__(256)
void qkv_kernel(const float* __restrict__ x,
                const float* __restrict__ gamma, const float* __restrict__ beta,
                const float* __restrict__ bq, const float* __restrict__ bk,
                const float* __restrict__ bv,
                const unsigned short* __restrict__ Wt,
                unsigned short* __restrict__ Qo, unsigned short* __restrict__ Ko,
                unsigned short* __restrict__ Vo)
{
  __shared__ unsigned char xs[32768];  // 128 rows x 256B (swizzled)
  __shared__ unsigned char wt[32768];  // 128 c-rows x 256B (swizzled)
  const int tid = threadIdx.x;
  const int lane = tid & 63;
  const int w = tid >> 6;
  const int l15 = lane & 15, kh = lane >> 4;
  const int n0 = blockIdx.x * 128;
  const int combo = blockIdx.y;
  const int mat = combo / 3, t = combo % 3;
  const float* B = (mat == 0) ? bq : (mat == 1) ? bk : bv;
  unsigned short* O = (mat == 0) ? Qo : (mat == 1) ? Ko : Vo;

  // ---- stage Wt slab (32KB) into LDS, swizzled ----
#pragma unroll
  for (int i = 0; i < 8; ++i) {
    int idx = i * 256 + tid;
    int rr = idx >> 4, ch = idx & 15;
    uint4 d4 = *(const uint4*)(Wt + (size_t)combo * 16384 + rr * 128 + ch * 8);
    *(uint4*)(wt + swz(rr * 256 + ch * 16)) = d4;
  }

  // ---- load x rows, LayerNorm, write bf16 into xs (2 threads/row) ----
  {
    int r = tid >> 1, hf = tid & 1;
    int rc = n0 + r; if (rc > NN - 1) rc = NN - 1;
    const float* xr = x + (size_t)rc * DD + hf * 64;
    float v[64];
    float s = 0.f, ss = 0.f;
#pragma unroll
    for (int i = 0; i < 16; ++i) {
      float4 q4 = ((const float4*)xr)[i];
      v[i * 4 + 0] = q4.x; v[i * 4 + 1] = q4.y; v[i * 4 + 2] = q4.z; v[i * 4 + 3] = q4.w;
      s += q4.x + q4.y + q4.z + q4.w;
      ss += q4.x * q4.x + q4.y * q4.y + q4.z * q4.z + q4.w * q4.w;
    }
    s += __shfl_xor(s, 1); ss += __shfl_xor(ss, 1);
    float mu = s * (1.f / 128.f);
    float rs = rsqrtf(ss * (1.f / 128.f) - mu * mu + 1e-5f);
#pragma unroll
    for (int i = 0; i < 16; ++i) {
      float4 g4 = ((const float4*)(gamma + hf * 64))[i];
      float4 b4 = ((const float4*)(beta + hf * 64))[i];
      ushort4 o;
      o.x = f2b((v[i * 4 + 0] - mu) * rs * g4.x + b4.x);
      o.y = f2b((v[i * 4 + 1] - mu) * rs * g4.y + b4.y);
      o.z = f2b((v[i * 4 + 2] - mu) * rs * g4.z + b4.z);
      o.w = f2b((v[i * 4 + 3] - mu) * rs * g4.w + b4.w);
      *(ushort4*)(xs + swz(r * 256 + hf * 128 + i * 8)) = o;
    }
  }

  // ---- init acc with bias ----
  f32x4 acc0[8], acc1[8];
#pragma unroll
  for (int ct = 0; ct < 8; ++ct) {
    int cc = ct * 16 + l15;
    float bb = B[((cc >> 5) * 3 + t) * 32 + (cc & 31)];
    f32x4 bi = {bb, bb, bb, bb};
    acc0[ct] = bi; acc1[ct] = bi;
  }
  __syncthreads();

  // ---- MFMA main loop: wave w owns rows w*32..w*32+31, all 128 cols ----
#pragma unroll
  for (int ks = 0; ks < 4; ++ks) {
    short8 a0 = *(const short8*)(xs + swz((w * 32 + l15) * 256 + ks * 64 + kh * 16));
    short8 a1 = *(const short8*)(xs + swz((w * 32 + 16 + l15) * 256 + ks * 64 + kh * 16));
#pragma unroll
    for (int ct = 0; ct < 8; ++ct) {
      short8 bf = *(const short8*)(wt + swz((ct * 16 + l15) * 256 + ks * 64 + kh * 16));
      acc0[ct] = __builtin_amdgcn_mfma_f32_16x16x32_bf16(a0, bf, acc0[ct], 0, 0, 0);
      acc1[ct] = __builtin_amdgcn_mfma_f32_16x16x32_bf16(a1, bf, acc1[ct], 0, 0, 0);
    }
  }

  // ---- epilogue: repack through LDS for coalesced bf16 stores ----
  __syncthreads();
#pragma unroll
  for (int mt = 0; mt < 2; ++mt)
#pragma unroll
    for (int ct = 0; ct < 8; ++ct)
#pragma unroll
      for (int rg = 0; rg < 4; ++rg) {
        int rr = w * 32 + mt * 16 + kh * 4 + rg;
        int cc = ct * 16 + l15;
        float val = mt ? acc1[ct][rg] : acc0[ct][rg];
        *(unsigned short*)(xs + swz(rr * 256 + cc * 2)) = f2b(val);
      }
  __syncthreads();
#pragma unroll
  for (int i = 0; i < 8; ++i) {
    int idx = i * 256 + tid;
    int rr = idx >> 4, ch = idx & 15;
    if (n0 + rr < NN) {
      uint4 d4 = *(const uint4*)(xs + swz(rr * 256 + ch * 16));
      *(uint4*)(O + ((size_t)t * NN + n0 + rr) * DD + ch * 8) = d4;
    }
  }
}

// ---------------------------------------------------------------
__global__ __launch_bounds__(256)
void hist_kernel(const int* __restrict__ ei, int* __restrict__ deg)
{
  int e = blockIdx.x * 256 + threadIdx.x;
  if (e < NE) atomicAdd(&deg[ei[NE + e]], 1);
}

// ---- two-level scan: part -> mid -> add ----
__global__ __launch_bounds__(256)
void scan_part(const int* __restrict__ deg, int* __restrict__ base, int* __restrict__ bsum)
{
  const int b = blockIdx.x, tid = threadIdx.x;
  int i = b * 256 + tid;
  int v = (i < NN) ? deg[i] : 0;
  int xv = v;
#pragma unroll
  for (int off = 1; off < 64; off <<= 1) {
    int y = __shfl_up(xv, off);
    if ((tid & 63) >= off) xv += y;
  }
  __shared__ int wsum[4];
  if ((tid & 63) == 63) wsum[tid >> 6] = xv;
  __syncthreads();
  int add = 0;
  if (tid >= 64)  add += wsum[0];
  if (tid >= 128) add += wsum[1];
  if (tid >= 192) add += wsum[2];
  xv += add;
  if (i < NN) base[i] = xv - v;   // local exclusive
  if (tid == 255) bsum[b] = xv;
}

__global__ __launch_bounds__(64)
void scan_mid(const int* __restrict__ bsum, int* __restrict__ boff, int nb)
{
  __shared__ int carry;
  if (threadIdx.x == 0) carry = 0;
  __syncthreads();
  for (int s = 0; s < nb; s += 64) {
    int i = s + threadIdx.x;
    int v = (i < nb) ? bsum[i] : 0;
    int xv = v;
#pragma unroll
    for (int off = 1; off < 64; off <<= 1) {
      int y = __shfl_up(xv, off);
      if (threadIdx.x >= (unsigned)off) xv += y;
    }
    int c = carry;
    if (i < nb) boff[i] = c + xv - v;
    __syncthreads();
    if (threadIdx.x == 63) carry = c + xv;
    __syncthreads();
  }
}

__global__ __launch_bounds__(256)
void scan_add(int* __restrict__ base, const int* __restrict__ boff)
{
  int i = blockIdx.x * 256 + threadIdx.x;
  if (i < NN) base[i] += boff[blockIdx.x];
  if (i == 0) base[NN] = NE;
}

// ---------------------------------------------------------------
// Edge attention scores + CSR scatter + per-block head max. bf16 Q/K.
// ---------------------------------------------------------------
__global__ __launch_bounds__(256)
void edge_att_kernel(const int* __restrict__ ei, const float* __restrict__ ev,
                     const float* __restrict__ m1, const float* __restrict__ m2,
                     const unsigned short* __restrict__ Q, const unsigned short* __restrict__ K,
                     const int* __restrict__ base, int* __restrict__ fill,
                     float* __restrict__ attp, int* __restrict__ code,
                     unsigned* __restrict__ blockmax)
{
  __shared__ unsigned smax[4];
  const int tid = threadIdx.x;
  if (tid < 4) smax[tid] = 0u;
  __syncthreads();

  const int g = blockIdx.x * 256 + tid;
  const int e = g >> 2;
  const int h = g & 3;
  const int src = ei[e];
  const int dst = ei[NE + e];
  const int t = (m1[e] > 0.5f) ? 1 : ((m2[e] > 0.5f) ? 2 : 0);

  const unsigned short* qr = Q + ((size_t)t * NN + dst) * DD + h * 32;
  const unsigned short* kr = K + ((size_t)t * NN + src) * DD + h * 32;
  float dot = 0.f;
#pragma unroll
  for (int i = 0; i < 4; ++i) {
    uint4 a = ((const uint4*)qr)[i];
    uint4 b = ((const uint4*)kr)[i];
    dot += pdot(a.x, b.x) + pdot(a.y, b.y) + pdot(a.z, b.z) + pdot(a.w, b.w);
  }
  float av = fabsf(ev[e]);
  float decay = exp2f(-0.15200309344504995f * av);      // 0.9^|v|
  float ap = dot * 0.17677669529663687f * decay;        // /sqrt(32)*decay

  int slot = 0;
  if (h == 0) slot = base[dst] + atomicAdd(&fill[dst], 1);
  slot = __shfl(slot, (tid & 63) & ~3);
  attp[(size_t)slot * 4 + h] = ap;
  if (h == 0) code[slot] = src | (t << 16);

  float m = ap;
  m = fmaxf(m, __shfl_xor(m, 4));
  m = fmaxf(m, __shfl_xor(m, 8));
  m = fmaxf(m, __shfl_xor(m, 16));
  m = fmaxf(m, __shfl_xor(m, 32));
  if ((tid & 63) < 4) atomicMax(&smax[h], enc_f(m));
  __syncthreads();
  if (tid < 4) blockmax[blockIdx.x * 4 + tid] = smax[tid];
}

__global__ __launch_bounds__(256)
void max_reduce_kernel(const unsigned* __restrict__ blockmax, float* __restrict__ gmax, int nb)
{
  __shared__ unsigned sm[4];
  const int tid = threadIdx.x;
  const int h = tid & 3;
  if (tid < 4) sm[tid] = 0u;
  __syncthreads();
  unsigned m = 0u;
  for (int i = tid; i < nb * 4; i += 256) m = max(m, blockmax[i]);
  atomicMax(&sm[h], m);
  __syncthreads();
  if (tid < 4) gmax[tid] = dec_f(sm[tid]);
}

// ---------------------------------------------------------------
// Per-node aggregation. bf16 V.
// ---------------------------------------------------------------
__global__ __launch_bounds__(128)
void node_kernel(const float* __restrict__ x, const unsigned short* __restrict__ V,
                 const float* __restrict__ attp, const int* __restrict__ code,
                 const int* __restrict__ base, const float* __restrict__ gmax,
                 float* __restrict__ out)
{
  const int n = blockIdx.x;
  const int c = threadIdx.x;
  const int h = c >> 5;
  const float mx = gmax[h];
  const int b0 = base[n], b1 = base[n + 1];
  float acc = 0.f, den = 0.f;
  for (int j = b0; j < b1; ++j) {
    int cd = code[j];
    int s = cd & 0xFFFF;
    int t = cd >> 16;
    float a = __expf(attp[(size_t)j * 4 + h] - mx);
    den += a;
    acc += a * b2f(V[((size_t)t * NN + s) * DD + c]);
  }
  float z = acc / (den + 1e-16f);
  float g = 0.5f * z * (1.0f + erff(z * 0.70710678118654752f));
  out[(size_t)n * DD + c] = x[(size_t)n * DD + c] + g;
}

// ---------------------------------------------------------------
extern "C" void kernel_launch(void* const* d_in, const int* in_sizes, int n_in,
                              void* d_out, int out_size, void* d_ws, size_t ws_size,
                              hipStream_t stream)
{
  const float* x     = (const float*)d_in[0];
  const int*   ei    = (const int*)d_in[1];
  const float* ev    = (const float*)d_in[2];
  const float* m1    = (const float*)d_in[5];  // diff_time_same_var -> t=1
  const float* m2    = (const float*)d_in[6];  // diff_time_diff_var -> t=2
  const float* gamma = (const float*)d_in[8];
  const float* beta  = (const float*)d_in[9];
  const float* Wq    = (const float*)d_in[10];
  const float* bq    = (const float*)d_in[11];
  const float* Wk    = (const float*)d_in[12];
  const float* bk    = (const float*)d_in[13];
  const float* Wv    = (const float*)d_in[14];
  const float* bv    = (const float*)d_in[15];
  float* out = (float*)d_out;

  // ---- workspace layout ----
  unsigned short* Q  = (unsigned short*)d_ws;        // 15,360,000 bf16
  unsigned short* Kb = Q  + (size_t)3 * NN * DD;
  unsigned short* Vb = Kb + (size_t)3 * NN * DD;
  unsigned short* Wt = Vb + (size_t)3 * NN * DD;     // 9*16384 bf16
  float* attp = (float*)(Wt + 9 * 16384);            // NE*4 f32
  int*   code = (int*)(attp + (size_t)NE * 4);       // NE
  int*   deg  = code + NE;                           // NN
  int*   fill = deg + NN;                            // NN
  int*   base = fill + NN;                           // NN+1
  int*   bsum = base + NN + 1;                       // 157
  int*   boff = bsum + 157;                          // 157
  unsigned* blockmax = (unsigned*)(boff + 157);      // 40000
  float* gmax = (float*)(blockmax + 40000);          // 4

  hipMemsetAsync(deg, 0, (size_t)2 * NN * sizeof(int), stream);  // deg + fill

  wt_kernel<<<9, 256, 0, stream>>>(Wq, Wk, Wv, Wt);
  qkv_kernel<<<dim3(313, 9), 256, 0, stream>>>(x, gamma, beta, bq, bk, bv, Wt, Q, Kb, Vb);
  hist_kernel<<<NE / 256, 256, 0, stream>>>(ei, deg);
  scan_part<<<157, 256, 0, stream>>>(deg, base, bsum);
  scan_mid<<<1, 64, 0, stream>>>(bsum, boff, 157);
  scan_add<<<157, 256, 0, stream>>>(base, boff);
  edge_att_kernel<<<(NE * 4) / 256, 256, 0, stream>>>(ei, ev, m1, m2, Q, Kb, base, fill, attp, code, blockmax);
  max_reduce_kernel<<<1, 256, 0, stream>>>(blockmax, gmax, (NE * 4) / 256);
  node_kernel<<<NN, 128, 0, stream>>>(x, Vb, attp, code, base, gmax, out);
}